// Round 6
// baseline (661.540 us; speedup 1.0000x reference)
//
#include <hip/hip_runtime.h>
#include <hip/hip_bf16.h>
#include <math.h>
#include <stdint.h>

#define DDIM 256
#define CAP  320
#define NCLS 50

typedef short bf16x8_t __attribute__((ext_vector_type(8)));  // 8 bf16 bit-pattern
typedef float f32x4_t  __attribute__((ext_vector_type(4)));

// global -> LDS direct copy, 16B/lane. LDS dest wave-uniform base + lane*16;
// global source per-lane. (HW-proven R2/R5)
__device__ __forceinline__ void gl_lds16(const void* g, void* l) {
  __builtin_amdgcn_global_load_lds(
      (__attribute__((address_space(1))) unsigned int*)(uintptr_t)g,
      (__attribute__((address_space(3))) unsigned int*)l,
      16, 0, 0);
}

__device__ __forceinline__ unsigned short bf16bits(float v) {
  __hip_bfloat16 h = __float2bfloat16(v);
  return *reinterpret_cast<unsigned short*>(&h);
}

// ------------------------------------------------- fused cast + col sumsq (v2)
// float4 loads (16B/lane), ushort4 bf16 stores (8B/lane), LDS partial reduce.
// thread t: rows r0+rsub, r0+rsub+4, ...; dims (t&63)*4 .. +3
__global__ void k_cast_colsq(const float* __restrict__ train,
                             __hip_bfloat16* __restrict__ tbf,
                             double* __restrict__ colsq, int N) {
  const int t = threadIdx.x;
  const int rsub = t >> 6;          // 0..3
  const int c4 = (t & 63) * 4;      // dim base
  const int nb = gridDim.x;
  int per = (N + nb - 1) / nb; per = (per + 3) & ~3;
  const int r0 = blockIdx.x * per;
  int r1 = r0 + per; if (r1 > N) r1 = N;
  double a0 = 0, a1 = 0, a2 = 0, a3 = 0;
  for (int r = r0 + rsub; r < r1; r += 4) {
    float4 v = *(const float4*)(train + (size_t)r * DDIM + c4);
    if (tbf) {
      ushort4 u;
      u.x = bf16bits(v.x); u.y = bf16bits(v.y);
      u.z = bf16bits(v.z); u.w = bf16bits(v.w);
      *(ushort4*)(tbf + (size_t)r * DDIM + c4) = u;
    }
    a0 = fma((double)v.x, (double)v.x, a0);
    a1 = fma((double)v.y, (double)v.y, a1);
    a2 = fma((double)v.z, (double)v.z, a2);
    a3 = fma((double)v.w, (double)v.w, a3);
  }
  __shared__ double red[4][DDIM];
  red[rsub][c4 + 0] = a0; red[rsub][c4 + 1] = a1;
  red[rsub][c4 + 2] = a2; red[rsub][c4 + 3] = a3;
  __syncthreads();
  // thread t owns dim t
  double s = red[0][t] + red[1][t] + red[2][t] + red[3][t];
  atomicAdd(&colsq[t], s);
}

// ------------------------------------------------- prep query
// qs[b][d] = (test[b][d]/max(||test[b]||,eps)) / max(colnorm[d],eps)
// qs_bf = bf16(qs);  tau[b] = 3.30 * ||qs[b]||  (filter threshold)
__global__ void k_prep(const float* __restrict__ test, const double* __restrict__ colsq,
                       float* __restrict__ qs, __hip_bfloat16* __restrict__ qs_bf,
                       float* __restrict__ tau, int B) {
  const int row = blockIdx.x, t = threadIdx.x;
  const int wid = t >> 6, lane = t & 63;
  __shared__ float ps[4];
  __shared__ float stot;
  float v = test[(size_t)row * DDIM + t];
  float ss = v * v;
#pragma unroll
  for (int o = 32; o > 0; o >>= 1) ss += __shfl_down(ss, o, 64);
  if (lane == 0) ps[wid] = ss;
  __syncthreads();
  if (t == 0) stot = ps[0] + ps[1] + ps[2] + ps[3];
  __syncthreads();
  float rn   = fmaxf(sqrtf(stot), 1e-12f);
  float coln = fmaxf(sqrtf((float)colsq[t]), 1e-12f);
  float qv   = (v / rn) / coln;
  qs[(size_t)row * DDIM + t] = qv;
  qs_bf[(size_t)row * DDIM + t] = __float2bfloat16(qv);
  float s2 = qv * qv;
#pragma unroll
  for (int o = 32; o > 0; o >>= 1) s2 += __shfl_down(s2, o, 64);
  if (lane == 0) ps[wid] = s2;
  __syncthreads();
  if (t == 0) tau[row] = 3.30f * sqrtf(ps[0] + ps[1] + ps[2] + ps[3]);
}

// ------------------------------------------------- MFMA filter GEMM v2
// B-stationary: block owns a 128-col stripe; full B stripe (128x256, 64KB) +
// tau (4KB) staged to LDS once -> 2 blocks/CU. Loop 8 row-panels x 8 K-steps
// with ZERO barriers: A frags loaded global->reg (per-lane 16B from
// L2-resident qs_bf) one step ahead; B frags via ds_read_b128.
// Wave layout 4x1: wave w = rows [p*128+w*32, +32), all 128 cols.
// Maps (HW-verified R5, absmax=0): A/B operand (lane,reg)->k identical:
// item=lane&15, k=(lane>>4)*8+j. C/D: col=lane&15, row=(lane>>4)*4+reg.
__global__ __launch_bounds__(256, 2)
void k_mfma(const __hip_bfloat16* __restrict__ qs_bf,
            const __hip_bfloat16* __restrict__ train_bf,
            const float* __restrict__ tau, int* __restrict__ cidx,
            int* __restrict__ cnt, int N, int B) {
  __shared__ __align__(16) char Bsh[65536];   // 64 groups (s*8+g) x 1024B
  __shared__ float tau_s[1024];               // B <= 1024
  const int tid = threadIdx.x;
  const int w = tid >> 6, lane = tid & 63;
  const int l15 = lane & 15, l4 = lane >> 4;
  const int col0 = blockIdx.x * 128;

  // stage B stripe: wave w stages groups w*16 .. w*16+15
#pragma unroll
  for (int i = 0; i < 16; ++i) {
    const int idx = w * 16 + i;
    const int s = idx >> 3, g = idx & 7;
    int c = col0 + g * 16 + l15; if (c >= N) c = N - 1;
    gl_lds16(train_bf + (size_t)c * DDIM + s * 32 + l4 * 8, Bsh + idx * 1024);
  }
  for (int i = tid; i < 1024; i += 256) {
    int rr = i; if (rr >= B) rr = B - 1;
    tau_s[i] = tau[rr];
  }
  __syncthreads();   // drains vmcnt(0): B stripe + tau resident; LDS read-only after

  const int npan = (B + 127) / 128;
  bf16x8_t afc[2], afn[2];
  {
    int r0 = w * 32 + l15;      if (r0 >= B) r0 = B - 1;
    int r1 = w * 32 + 16 + l15; if (r1 >= B) r1 = B - 1;
    afc[0] = *(const bf16x8_t*)(qs_bf + (size_t)r0 * DDIM + l4 * 8);
    afc[1] = *(const bf16x8_t*)(qs_bf + (size_t)r1 * DDIM + l4 * 8);
  }

  for (int p = 0; p < npan; ++p) {
    f32x4_t acc[2][8];
#pragma unroll
    for (int m = 0; m < 2; ++m)
#pragma unroll
      for (int n = 0; n < 8; ++n) acc[m][n] = (f32x4_t){0.f, 0.f, 0.f, 0.f};

#pragma unroll
    for (int s = 0; s < 8; ++s) {
      // prefetch next step's A frags (next panel's step 0 at s==7)
      const int sp1 = (s + 1) & 7;
      const int pn = (s == 7) ? (p + 1 < npan ? p + 1 : p) : p;
      {
        int r0 = pn * 128 + w * 32 + l15;      if (r0 >= B) r0 = B - 1;
        int r1 = pn * 128 + w * 32 + 16 + l15; if (r1 >= B) r1 = B - 1;
        const size_t ko = (size_t)sp1 * 32 + l4 * 8;
        afn[0] = *(const bf16x8_t*)(qs_bf + (size_t)r0 * DDIM + ko);
        afn[1] = *(const bf16x8_t*)(qs_bf + (size_t)r1 * DDIM + ko);
      }
#pragma unroll
      for (int n = 0; n < 8; ++n) {
        bf16x8_t bf = *(const bf16x8_t*)(Bsh + (s * 8 + n) * 1024 + lane * 16);
        acc[0][n] = __builtin_amdgcn_mfma_f32_16x16x32_bf16(afc[0], bf, acc[0][n], 0, 0, 0);
        acc[1][n] = __builtin_amdgcn_mfma_f32_16x16x32_bf16(afc[1], bf, acc[1][n], 0, 0, 0);
      }
      afc[0] = afn[0]; afc[1] = afn[1];
    }

    // panel epilogue: threshold-append (rare)
#pragma unroll
    for (int m = 0; m < 2; ++m) {
#pragma unroll
      for (int n = 0; n < 8; ++n) {
        const int coln = col0 + n * 16 + l15;
        if (coln < N) {
#pragma unroll
          for (int r = 0; r < 4; ++r) {
            const int rl = p * 128 + w * 32 + m * 16 + l4 * 4 + r;
            if (rl < B && acc[m][n][r] > tau_s[rl]) {
              int pos = atomicAdd(&cnt[rl], 1);
              if (pos < CAP) cidx[(size_t)rl * CAP + pos] = coln;
            }
          }
        }
      }
    }
  }
}

// ------------------------------------------------- fp32 filter (ws fallback)
#define DOT4(ACC, A, Bv)                                                     \
  ACC = fmaf((A).x, (Bv).x, ACC); ACC = fmaf((A).y, (Bv).y, ACC);            \
  ACC = fmaf((A).z, (Bv).z, ACC); ACC = fmaf((A).w, (Bv).w, ACC);

__global__ __launch_bounds__(256, 4)
void k_gemm(const float* __restrict__ train, const float* __restrict__ qs,
            const float* __restrict__ tau, int* __restrict__ cidx,
            int* __restrict__ cnt, int N, int B, int tpc) {
  __shared__ float4 As4[8 * 128];
  __shared__ float4 Bs4[8 * 64];
  const int tid = threadIdx.x;
  const int tx = tid & 15, ty = tid >> 4;
  const int wid = tid >> 6, lane = tid & 63;
  const int row0 = blockIdx.y * 128;
  const int colbase = blockIdx.x * tpc * 64;
  float tau_r[8];
#pragma unroll
  for (int i = 0; i < 8; ++i) {
    int r = row0 + ty + 16 * i; if (r >= B) r = B - 1;
    tau_r[i] = tau[r];
  }
  int rL = row0 + lane;      if (rL >= B) rL = B - 1;
  int rH = row0 + 64 + lane; if (rH >= B) rH = B - 1;
  const float* aptrL = qs + (size_t)rL * DDIM;
  const float* aptrH = qs + (size_t)rH * DDIM;
  for (int tile = 0; tile < tpc; ++tile) {
    const int col0 = colbase + tile * 64;
    if (col0 >= N) break;
    int bcol = col0 + lane; if (bcol >= N) bcol = N - 1;
    const float* bptr = train + (size_t)bcol * DDIM;
    float acc[8][4];
#pragma unroll
    for (int i = 0; i < 8; ++i)
#pragma unroll
      for (int j = 0; j < 4; ++j) acc[i][j] = 0.f;
    for (int s = 0; s < 8; ++s) {
      const int kk0 = s * 32;
      __syncthreads();
#pragma unroll
      for (int j = 0; j < 4; ++j) {
        const int slot = wid + 4 * j;
        const int m = slot >> 1, half = slot & 1;
        gl_lds16((half ? aptrH : aptrL) + kk0 + 4 * m, &As4[m * 128 + half * 64]);
      }
#pragma unroll
      for (int j = 0; j < 2; ++j) {
        const int m = wid + 4 * j;
        gl_lds16(bptr + kk0 + 4 * m, &Bs4[m * 64]);
      }
      __syncthreads();
#pragma unroll
      for (int k4 = 0; k4 < 8; ++k4) {
        float4 a[8], b[4];
#pragma unroll
        for (int i = 0; i < 8; ++i) a[i] = As4[k4 * 128 + ty + 16 * i];
#pragma unroll
        for (int j = 0; j < 4; ++j) b[j] = Bs4[k4 * 64 + tx + 16 * j];
#pragma unroll
        for (int i = 0; i < 8; ++i)
#pragma unroll
          for (int j = 0; j < 4; ++j) { DOT4(acc[i][j], a[i], b[j]) }
      }
    }
#pragma unroll
    for (int i = 0; i < 8; ++i) {
      const int r = row0 + ty + 16 * i;
#pragma unroll
      for (int j = 0; j < 4; ++j) {
        const int c = col0 + tx + 16 * j;
        if (acc[i][j] > tau_r[i] && c < N && r < B) {
          int p = atomicAdd(&cnt[r], 1);
          if (p < CAP) cidx[(size_t)r * CAP + p] = c;
        }
      }
    }
  }
}

// ------------------------------------------------- fallback full rescan
__global__ void k_fallback(const float* __restrict__ train, const float* __restrict__ qs,
                           int* __restrict__ cidx, int* __restrict__ cnt, int N) {
  const int row = blockIdx.x;
  const int t = threadIdx.x;
  const int c0 = cnt[row];
  if (c0 >= 10 && c0 <= CAP) return;
  __shared__ float q[DDIM];
  if (t < DDIM) q[t] = qs[(size_t)row * DDIM + t];
  __syncthreads();
  float lv[10]; int li[10];
#pragma unroll
  for (int k = 0; k < 10; ++k) { lv[k] = -INFINITY; li[k] = 0x7FFFFFFF; }
  for (int c = t; c < N; c += 256) {
    const float* tr = train + (size_t)c * DDIM;
    float s = 0.f;
    for (int d = 0; d < DDIM; ++d) s = fmaf(q[d], tr[d], s);
    if (s > lv[9]) {
      int p = 9;
      while (p > 0 && s > lv[p - 1]) { lv[p] = lv[p - 1]; li[p] = li[p - 1]; --p; }
      lv[p] = s; li[p] = c;
    }
  }
  __shared__ float rv[256]; __shared__ int ri[256]; __shared__ int rt_[256];
  __shared__ int topi[10];
  int pt = 0;
  for (int k = 0; k < 10; ++k) {
    rv[t] = (pt < 10) ? lv[pt] : -INFINITY;
    ri[t] = (pt < 10) ? li[pt] : 0x7FFFFFFF;
    rt_[t] = t;
    __syncthreads();
    for (int s2 = 128; s2 > 0; s2 >>= 1) {
      if (t < s2) {
        float ov = rv[t + s2]; int oi = ri[t + s2];
        if (ov > rv[t] || (ov == rv[t] && oi < ri[t])) {
          rv[t] = ov; ri[t] = oi; rt_[t] = rt_[t + s2];
        }
      }
      __syncthreads();
    }
    const int win = rt_[0];
    if (t == 0) topi[k] = ri[0];
    __syncthreads();
    if (t == win) ++pt;
  }
  if (t < 10) cidx[(size_t)row * CAP + t] = topi[t];
  if (t == 0) cnt[row] = 10;
}

// ------------------------------------------------- fp64 rescore
__global__ void k_rescore(const float* __restrict__ train, const float* __restrict__ qs,
                          const int* __restrict__ cidx, const int* __restrict__ cnt,
                          double* __restrict__ dval) {
  const int row = blockIdx.x;
  const int t = threadIdx.x, wid = t >> 6, lane = t & 63;
  __shared__ float qsh[DDIM];
  if (t < DDIM) qsh[t] = qs[(size_t)row * DDIM + t];
  __syncthreads();
  int n = cnt[row]; if (n > CAP) n = CAP;
  for (int ci = wid; ci < n; ci += 4) {
    const int c = cidx[(size_t)row * CAP + ci];
    const float4 tv = *(const float4*)(train + (size_t)c * DDIM + lane * 4);
    const float4 qv = *(const float4*)(qsh + lane * 4);
    double s = (double)tv.x * qv.x + (double)tv.y * qv.y +
               (double)tv.z * qv.z + (double)tv.w * qv.w;
#pragma unroll
    for (int o = 32; o > 0; o >>= 1) s += __shfl_down(s, o, 64);
    if (lane == 0) dval[(size_t)row * CAP + ci] = s;
  }
}

// ------------------------------------------------- finalize
__global__ void k_finalize(const double* __restrict__ dval, const int* __restrict__ cidx,
                           const int* __restrict__ cnt, const int* __restrict__ labels,
                           float* __restrict__ out) {
  const int row = blockIdx.x;
  const int t = threadIdx.x;
  int n = cnt[row]; if (n > CAP) n = CAP;
  __shared__ double sv[CAP]; __shared__ int si[CAP];
  for (int i = t; i < CAP; i += 256) {
    sv[i] = (i < n) ? dval[(size_t)row * CAP + i] : -INFINITY;
    si[i] = (i < n) ? cidx[(size_t)row * CAP + i] : 0x7FFFFFFF;
  }
  __syncthreads();
  __shared__ double rv[256]; __shared__ int ri[256]; __shared__ int rp[256];
  __shared__ double topv[10]; __shared__ int topl[10];
  __shared__ int wpos;
  for (int k = 0; k < 10; ++k) {
    double bv = sv[t]; int bi = si[t]; int bp = t;
    if (t + 256 < CAP) {
      double v2 = sv[t + 256]; int i2 = si[t + 256];
      if (v2 > bv || (v2 == bv && i2 < bi)) { bv = v2; bi = i2; bp = t + 256; }
    }
    rv[t] = bv; ri[t] = bi; rp[t] = bp;
    __syncthreads();
    for (int s2 = 128; s2 > 0; s2 >>= 1) {
      if (t < s2) {
        double ov = rv[t + s2]; int oi = ri[t + s2];
        if (ov > rv[t] || (ov == rv[t] && oi < ri[t])) {
          rv[t] = ov; ri[t] = oi; rp[t] = rp[t + s2];
        }
      }
      __syncthreads();
    }
    if (t == 0) { topv[k] = rv[0]; topl[k] = ri[0]; wpos = rp[0]; }
    __syncthreads();
    if (t == 0) sv[wpos] = -INFINITY;
    __syncthreads();
  }
  __shared__ double oc[NCLS];
  if (t < NCLS) oc[t] = 0.0;
  __syncthreads();
  if (t == 0) {
    const double m = topv[0];
    double w[10]; double ssum = 0.0;
#pragma unroll
    for (int k = 0; k < 10; ++k) { w[k] = exp((topv[k] - m) / 0.07); ssum += w[k]; }
#pragma unroll
    for (int k = 0; k < 10; ++k) oc[labels[topl[k]]] += w[k] / ssum;
  }
  __syncthreads();
  if (t < NCLS) out[(size_t)row * NCLS + t] = (float)oc[t];
}

// ------------------------------------------------- launch
extern "C" void kernel_launch(void* const* d_in, const int* in_sizes, int n_in,
                              void* d_out, int out_size, void* d_ws, size_t ws_size,
                              hipStream_t stream) {
  const float* test   = (const float*)d_in[0];
  const float* train  = (const float*)d_in[1];
  const int*   labels = (const int*)d_in[2];
  float* out = (float*)d_out;
  const int B = in_sizes[0] / DDIM;   // 1024
  const int N = in_sizes[2];          // 200000
  (void)n_in; (void)out_size;

  char* w = (char*)d_ws;
  size_t off = 0;
  auto alloc = [&](size_t bytes) {
    size_t o = off; off = (off + bytes + 255) & ~(size_t)255; return o;
  };
  double* colsq = (double*)(w + alloc(2048));
  int*    cnt   = (int*)(w + alloc((size_t)B * 4));
  float*  tau   = (float*)(w + alloc((size_t)B * 4));
  float*  qs    = (float*)(w + alloc((size_t)B * DDIM * 4));
  __hip_bfloat16* qs_bf = (__hip_bfloat16*)(w + alloc((size_t)B * DDIM * 2));
  int*    cidx  = (int*)(w + alloc((size_t)B * CAP * 4));
  double* dval  = (double*)(w + alloc((size_t)B * CAP * 8));
  __hip_bfloat16* train_bf = (__hip_bfloat16*)(w + alloc((size_t)N * DDIM * 2));
  const bool use_mfma = (ws_size >= off);

  hipMemsetAsync(d_ws, 0, 2048 + (size_t)B * 4, stream);   // colsq + cnt

  if (use_mfma) {
    hipLaunchKernelGGL(k_cast_colsq, dim3(512), dim3(256), 0, stream,
                       train, train_bf, colsq, N);
    hipLaunchKernelGGL(k_prep, dim3(B), dim3(256), 0, stream,
                       test, colsq, qs, qs_bf, tau, B);
    hipLaunchKernelGGL(k_mfma, dim3((N + 127) / 128), dim3(256), 0, stream,
                       qs_bf, train_bf, tau, cidx, cnt, N, B);
  } else {
    hipLaunchKernelGGL(k_cast_colsq, dim3(512), dim3(256), 0, stream,
                       train, (__hip_bfloat16*)nullptr, colsq, N);
    hipLaunchKernelGGL(k_prep, dim3(B), dim3(256), 0, stream,
                       test, colsq, qs, qs_bf, tau, B);
    const int CT = (N + 63) / 64;
    const int rb = (B + 127) / 128;
    int bx = 2048 / (rb > 0 ? rb : 1); if (bx < 1) bx = 1;
    int tpc = (CT + bx - 1) / bx;
    int chunks = (CT + tpc - 1) / tpc;
    hipLaunchKernelGGL(k_gemm, dim3(chunks, rb), dim3(256), 0, stream,
                       train, qs, tau, cidx, cnt, N, B, tpc);
  }

  hipLaunchKernelGGL(k_fallback, dim3(B), dim3(256), 0, stream,
                     train, qs, cidx, cnt, N);
  hipLaunchKernelGGL(k_rescore,  dim3(B), dim3(256), 0, stream,
                     train, qs, cidx, cnt, dval);
  hipLaunchKernelGGL(k_finalize, dim3(B), dim3(256), 0, stream,
                     dval, cidx, cnt, labels, out);
}

// Round 8
// 633.648 us; speedup vs baseline: 1.0440x; 1.0440x over previous
//
#include <hip/hip_runtime.h>
#include <hip/hip_bf16.h>
#include <math.h>
#include <stdint.h>

#define DDIM 256
#define CAP  320
#define NCLS 50

typedef short bf16x8_t __attribute__((ext_vector_type(8)));  // 8 bf16 bit-pattern
typedef float f32x4_t  __attribute__((ext_vector_type(4)));

// global -> LDS direct copy, 16B/lane. LDS dest wave-uniform base + lane*16;
// global source per-lane. (HW-proven R2/R5/R6)
__device__ __forceinline__ void gl_lds16(const void* g, void* l) {
  __builtin_amdgcn_global_load_lds(
      (__attribute__((address_space(1))) unsigned int*)(uintptr_t)g,
      (__attribute__((address_space(3))) unsigned int*)l,
      16, 0, 0);
}

__device__ __forceinline__ unsigned short bf16bits(float v) {
  __hip_bfloat16 h = __float2bfloat16(v);
  return *reinterpret_cast<unsigned short*>(&h);
}

// ------------------------------------------------- fused cast + col sumsq
// float4 loads, ushort4 bf16 stores, LDS partial reduce -> 1 atomic/dim/block
__global__ void k_cast_colsq(const float* __restrict__ train,
                             __hip_bfloat16* __restrict__ tbf,
                             double* __restrict__ colsq, int N) {
  const int t = threadIdx.x;
  const int rsub = t >> 6;          // 0..3
  const int c4 = (t & 63) * 4;      // dim base
  const int nb = gridDim.x;
  int per = (N + nb - 1) / nb; per = (per + 3) & ~3;
  const int r0 = blockIdx.x * per;
  int r1 = r0 + per; if (r1 > N) r1 = N;
  double a0 = 0, a1 = 0, a2 = 0, a3 = 0;
  for (int r = r0 + rsub; r < r1; r += 4) {
    float4 v = *(const float4*)(train + (size_t)r * DDIM + c4);
    if (tbf) {
      ushort4 u;
      u.x = bf16bits(v.x); u.y = bf16bits(v.y);
      u.z = bf16bits(v.z); u.w = bf16bits(v.w);
      *(ushort4*)(tbf + (size_t)r * DDIM + c4) = u;
    }
    a0 = fma((double)v.x, (double)v.x, a0);
    a1 = fma((double)v.y, (double)v.y, a1);
    a2 = fma((double)v.z, (double)v.z, a2);
    a3 = fma((double)v.w, (double)v.w, a3);
  }
  __shared__ double red[4][DDIM];
  red[rsub][c4 + 0] = a0; red[rsub][c4 + 1] = a1;
  red[rsub][c4 + 2] = a2; red[rsub][c4 + 3] = a3;
  __syncthreads();
  double s = red[0][t] + red[1][t] + red[2][t] + red[3][t];
  atomicAdd(&colsq[t], s);
}

// ------------------------------------------------- prep query
__global__ void k_prep(const float* __restrict__ test, const double* __restrict__ colsq,
                       float* __restrict__ qs, __hip_bfloat16* __restrict__ qs_bf,
                       float* __restrict__ tau, int B) {
  const int row = blockIdx.x, t = threadIdx.x;
  const int wid = t >> 6, lane = t & 63;
  __shared__ float ps[4];
  __shared__ float stot;
  float v = test[(size_t)row * DDIM + t];
  float ss = v * v;
#pragma unroll
  for (int o = 32; o > 0; o >>= 1) ss += __shfl_down(ss, o, 64);
  if (lane == 0) ps[wid] = ss;
  __syncthreads();
  if (t == 0) stot = ps[0] + ps[1] + ps[2] + ps[3];
  __syncthreads();
  float rn   = fmaxf(sqrtf(stot), 1e-12f);
  float coln = fmaxf(sqrtf((float)colsq[t]), 1e-12f);
  float qv   = (v / rn) / coln;
  qs[(size_t)row * DDIM + t] = qv;
  qs_bf[(size_t)row * DDIM + t] = __float2bfloat16(qv);
  float s2 = qv * qv;
#pragma unroll
  for (int o = 32; o > 0; o >>= 1) s2 += __shfl_down(s2, o, 64);
  if (lane == 0) ps[wid] = s2;
  __syncthreads();
  if (t == 0) tau[row] = 3.30f * sqrtf(ps[0] + ps[1] + ps[2] + ps[3]);
}

// ------------------------------------------------- MFMA filter GEMM v3
// B-stationary 128-col stripe in LDS (staged once). Per 128-row panel:
// bulk-load the wave's A panel (16x 16B global loads -> 64 VGPR), then
// 8 K-steps of {8 batched ds_read_b128 -> 16 MFMA} with ZERO global deps.
// Maps HW-verified (R5/R6 absmax=0): A/B operand item=lane&15,
// k=(lane>>4)*8+j (identical for A and B => k-order invariant);
// C/D col=lane&15, row=(lane>>4)*4+reg.
__global__ __launch_bounds__(256, 2)
void k_mfma(const __hip_bfloat16* __restrict__ qs_bf,
            const __hip_bfloat16* __restrict__ train_bf,
            const float* __restrict__ tau, int* __restrict__ cidx,
            int* __restrict__ cnt, int N, int B) {
  __shared__ __align__(16) char Bsh[65536];   // 64 groups (s*8+g) x 1024B
  __shared__ float tau_s[1024];               // B <= 1024
  const int tid = threadIdx.x;
  const int w = tid >> 6, lane = tid & 63;
  const int l15 = lane & 15, l4 = lane >> 4;
  const int col0 = blockIdx.x * 128;

  // stage B stripe once: wave w stages groups w*16 .. w*16+15
#pragma unroll
  for (int i = 0; i < 16; ++i) {
    const int idx = w * 16 + i;
    const int s = idx >> 3, g = idx & 7;
    int c = col0 + g * 16 + l15; if (c >= N) c = N - 1;
    gl_lds16(train_bf + (size_t)c * DDIM + s * 32 + l4 * 8, Bsh + idx * 1024);
  }
  for (int i = tid; i < 1024; i += 256) {
    int rr = i; if (rr >= B) rr = B - 1;
    tau_s[i] = tau[rr];
  }
  __syncthreads();   // drains vmcnt(0): B stripe + tau resident; read-only after

  const int npan = (B + 127) / 128;
  for (int p = 0; p < npan; ++p) {
    // bulk A panel -> registers (in-order completion; consumed s=0..7)
    int r0 = p * 128 + w * 32 + l15;      if (r0 >= B) r0 = B - 1;
    int r1 = p * 128 + w * 32 + 16 + l15; if (r1 >= B) r1 = B - 1;
    const __hip_bfloat16* a0 = qs_bf + (size_t)r0 * DDIM + l4 * 8;
    const __hip_bfloat16* a1 = qs_bf + (size_t)r1 * DDIM + l4 * 8;
    bf16x8_t ap[8][2];
#pragma unroll
    for (int s = 0; s < 8; ++s) {
      ap[s][0] = *(const bf16x8_t*)(a0 + s * 32);
      ap[s][1] = *(const bf16x8_t*)(a1 + s * 32);
    }

    f32x4_t acc[2][8];
#pragma unroll
    for (int m = 0; m < 2; ++m)
#pragma unroll
      for (int n = 0; n < 8; ++n) acc[m][n] = (f32x4_t){0.f, 0.f, 0.f, 0.f};

#pragma unroll
    for (int s = 0; s < 8; ++s) {
      bf16x8_t bfr[8];                      // batched reads -> counted lgkmcnt
#pragma unroll
      for (int n = 0; n < 8; ++n)
        bfr[n] = *(const bf16x8_t*)(Bsh + (s * 8 + n) * 1024 + lane * 16);
#pragma unroll
      for (int n = 0; n < 8; ++n) {
        acc[0][n] = __builtin_amdgcn_mfma_f32_16x16x32_bf16(ap[s][0], bfr[n], acc[0][n], 0, 0, 0);
        acc[1][n] = __builtin_amdgcn_mfma_f32_16x16x32_bf16(ap[s][1], bfr[n], acc[1][n], 0, 0, 0);
      }
    }

    // panel epilogue: threshold-append (rare). HW-verified C/D map.
#pragma unroll
    for (int m = 0; m < 2; ++m) {
#pragma unroll
      for (int n = 0; n < 8; ++n) {
        const int coln = col0 + n * 16 + l15;
        if (coln < N) {
#pragma unroll
          for (int r = 0; r < 4; ++r) {
            const int rl = p * 128 + w * 32 + m * 16 + l4 * 4 + r;
            if (rl < B && acc[m][n][r] > tau_s[rl]) {
              int pos = atomicAdd(&cnt[rl], 1);
              if (pos < CAP) cidx[(size_t)rl * CAP + pos] = coln;
            }
          }
        }
      }
    }
  }
}

// ------------------------------------------------- fp32 filter (ws fallback)
#define DOT4(ACC, A, Bv)                                                     \
  ACC = fmaf((A).x, (Bv).x, ACC); ACC = fmaf((A).y, (Bv).y, ACC);            \
  ACC = fmaf((A).z, (Bv).z, ACC); ACC = fmaf((A).w, (Bv).w, ACC);

__global__ __launch_bounds__(256, 4)
void k_gemm(const float* __restrict__ train, const float* __restrict__ qs,
            const float* __restrict__ tau, int* __restrict__ cidx,
            int* __restrict__ cnt, int N, int B, int tpc) {
  __shared__ float4 As4[8 * 128];
  __shared__ float4 Bs4[8 * 64];
  const int tid = threadIdx.x;
  const int tx = tid & 15, ty = tid >> 4;
  const int wid = tid >> 6, lane = tid & 63;
  const int row0 = blockIdx.y * 128;
  const int colbase = blockIdx.x * tpc * 64;
  float tau_r[8];
#pragma unroll
  for (int i = 0; i < 8; ++i) {
    int r = row0 + ty + 16 * i; if (r >= B) r = B - 1;
    tau_r[i] = tau[r];
  }
  int rL = row0 + lane;      if (rL >= B) rL = B - 1;
  int rH = row0 + 64 + lane; if (rH >= B) rH = B - 1;
  const float* aptrL = qs + (size_t)rL * DDIM;
  const float* aptrH = qs + (size_t)rH * DDIM;
  for (int tile = 0; tile < tpc; ++tile) {
    const int col0 = colbase + tile * 64;
    if (col0 >= N) break;
    int bcol = col0 + lane; if (bcol >= N) bcol = N - 1;
    const float* bptr = train + (size_t)bcol * DDIM;
    float acc[8][4];
#pragma unroll
    for (int i = 0; i < 8; ++i)
#pragma unroll
      for (int j = 0; j < 4; ++j) acc[i][j] = 0.f;
    for (int s = 0; s < 8; ++s) {
      const int kk0 = s * 32;
      __syncthreads();
#pragma unroll
      for (int j = 0; j < 4; ++j) {
        const int slot = wid + 4 * j;
        const int m = slot >> 1, half = slot & 1;
        gl_lds16((half ? aptrH : aptrL) + kk0 + 4 * m, &As4[m * 128 + half * 64]);
      }
#pragma unroll
      for (int j = 0; j < 2; ++j) {
        const int m = wid + 4 * j;
        gl_lds16(bptr + kk0 + 4 * m, &Bs4[m * 64]);
      }
      __syncthreads();
#pragma unroll
      for (int k4 = 0; k4 < 8; ++k4) {
        float4 a[8], b[4];
#pragma unroll
        for (int i = 0; i < 8; ++i) a[i] = As4[k4 * 128 + ty + 16 * i];
#pragma unroll
        for (int j = 0; j < 4; ++j) b[j] = Bs4[k4 * 64 + tx + 16 * j];
#pragma unroll
        for (int i = 0; i < 8; ++i)
#pragma unroll
          for (int j = 0; j < 4; ++j) { DOT4(acc[i][j], a[i], b[j]) }
      }
    }
#pragma unroll
    for (int i = 0; i < 8; ++i) {
      const int r = row0 + ty + 16 * i;
#pragma unroll
      for (int j = 0; j < 4; ++j) {
        const int c = col0 + tx + 16 * j;
        if (acc[i][j] > tau_r[i] && c < N && r < B) {
          int p = atomicAdd(&cnt[r], 1);
          if (p < CAP) cidx[(size_t)r * CAP + p] = c;
        }
      }
    }
  }
}

// ------------------------------------------------- fused tail
// Per row: (rare) full rescan if cnt bad; fp64 rescore of candidates (LDS);
// exact top-10 (value desc, index asc = lax.top_k); softmax; label scatter.
__global__ void k_tail(const float* __restrict__ train, const float* __restrict__ qs,
                       const int* __restrict__ cidx, const int* __restrict__ cnt,
                       const int* __restrict__ labels, float* __restrict__ out, int N) {
  const int row = blockIdx.x;
  const int t = threadIdx.x;      // 256
  const int wv = t >> 6, lane = t & 63;
  __shared__ float qsh[DDIM];
  __shared__ int si[CAP];
  __shared__ double sv[CAP];
  if (t < DDIM) qsh[t] = qs[(size_t)row * DDIM + t];
  int n = cnt[row];                       // block-uniform
  const bool bad = (n < 10 || n > CAP);
  for (int i = t; i < CAP; i += 256) {
    si[i] = (!bad && i < n) ? cidx[(size_t)row * CAP + i] : 0x7FFFFFFF;
    sv[i] = -INFINITY;
  }
  __syncthreads();

  if (bad) {                              // statistically never; exact rescan
    float lv[10]; int li[10];
#pragma unroll
    for (int k = 0; k < 10; ++k) { lv[k] = -INFINITY; li[k] = 0x7FFFFFFF; }
    for (int c = t; c < N; c += 256) {
      const float* tr = train + (size_t)c * DDIM;
      float s = 0.f;
      for (int d = 0; d < DDIM; ++d) s = fmaf(qsh[d], tr[d], s);
      if (s > lv[9]) {
        int p = 9;
        while (p > 0 && s > lv[p - 1]) { lv[p] = lv[p - 1]; li[p] = li[p - 1]; --p; }
        lv[p] = s; li[p] = c;
      }
    }
    __shared__ float rv[256]; __shared__ int ri[256]; __shared__ int rt_[256];
    int pt = 0;
    for (int k = 0; k < 10; ++k) {
      rv[t] = (pt < 10) ? lv[pt] : -INFINITY;
      ri[t] = (pt < 10) ? li[pt] : 0x7FFFFFFF;
      rt_[t] = t;
      __syncthreads();
      for (int s2 = 128; s2 > 0; s2 >>= 1) {
        if (t < s2) {
          float ov = rv[t + s2]; int oi = ri[t + s2];
          if (ov > rv[t] || (ov == rv[t] && oi < ri[t])) {
            rv[t] = ov; ri[t] = oi; rt_[t] = rt_[t + s2];
          }
        }
        __syncthreads();
      }
      const int win = rt_[0];
      if (t == 0) si[k] = ri[0];
      __syncthreads();
      if (t == win) ++pt;
    }
    n = 10;
    __syncthreads();
  }
  int nn = n; if (nn > CAP) nn = CAP;

  // fp64 rescore: one wave per candidate
  for (int ci = wv; ci < nn; ci += 4) {
    const int c = si[ci];
    const float4 tv = *(const float4*)(train + (size_t)c * DDIM + lane * 4);
    const float4 qv = *(const float4*)(qsh + lane * 4);
    double s = (double)tv.x * qv.x + (double)tv.y * qv.y +
               (double)tv.z * qv.z + (double)tv.w * qv.w;
#pragma unroll
    for (int o = 32; o > 0; o >>= 1) s += __shfl_down(s, o, 64);
    if (lane == 0) sv[ci] = s;
  }
  __syncthreads();

  // exact top-10 with lax.top_k tie-break
  __shared__ double rv2[256]; __shared__ int ri2[256]; __shared__ int rp2[256];
  __shared__ double topv[10]; __shared__ int topl[10];
  __shared__ int wpos;
  for (int k = 0; k < 10; ++k) {
    double bv = sv[t]; int bi = si[t]; int bp = t;
    if (t + 256 < CAP) {
      double v2 = sv[t + 256]; int i2 = si[t + 256];
      if (v2 > bv || (v2 == bv && i2 < bi)) { bv = v2; bi = i2; bp = t + 256; }
    }
    rv2[t] = bv; ri2[t] = bi; rp2[t] = bp;
    __syncthreads();
    for (int s2 = 128; s2 > 0; s2 >>= 1) {
      if (t < s2) {
        double ov = rv2[t + s2]; int oi = ri2[t + s2];
        if (ov > rv2[t] || (ov == rv2[t] && oi < ri2[t])) {
          rv2[t] = ov; ri2[t] = oi; rp2[t] = rp2[t + s2];
        }
      }
      __syncthreads();
    }
    if (t == 0) { topv[k] = rv2[0]; topl[k] = ri2[0]; wpos = rp2[0]; }
    __syncthreads();
    if (t == 0) sv[wpos] = -INFINITY;
    __syncthreads();
  }

  __shared__ double oc[NCLS];
  if (t < NCLS) oc[t] = 0.0;
  __syncthreads();
  if (t == 0) {
    const double m = topv[0];
    double w[10]; double ssum = 0.0;
#pragma unroll
    for (int k = 0; k < 10; ++k) { w[k] = exp((topv[k] - m) / 0.07); ssum += w[k]; }
#pragma unroll
    for (int k = 0; k < 10; ++k) oc[labels[topl[k]]] += w[k] / ssum;
  }
  __syncthreads();
  if (t < NCLS) out[(size_t)row * NCLS + t] = (float)oc[t];
}

// ------------------------------------------------- launch
extern "C" void kernel_launch(void* const* d_in, const int* in_sizes, int n_in,
                              void* d_out, int out_size, void* d_ws, size_t ws_size,
                              hipStream_t stream) {
  const float* test   = (const float*)d_in[0];
  const float* train  = (const float*)d_in[1];
  const int*   labels = (const int*)d_in[2];
  float* out = (float*)d_out;
  const int B = in_sizes[0] / DDIM;   // 1024
  const int N = in_sizes[2];          // 200000
  (void)n_in; (void)out_size;

  char* w = (char*)d_ws;
  size_t off = 0;
  auto alloc = [&](size_t bytes) {
    size_t o = off; off = (off + bytes + 255) & ~(size_t)255; return o;
  };
  double* colsq = (double*)(w + alloc(2048));
  int*    cnt   = (int*)(w + alloc((size_t)B * 4));
  float*  tau   = (float*)(w + alloc((size_t)B * 4));
  float*  qs    = (float*)(w + alloc((size_t)B * DDIM * 4));
  __hip_bfloat16* qs_bf = (__hip_bfloat16*)(w + alloc((size_t)B * DDIM * 2));
  int*    cidx  = (int*)(w + alloc((size_t)B * CAP * 4));
  __hip_bfloat16* train_bf = (__hip_bfloat16*)(w + alloc((size_t)N * DDIM * 2));
  const bool use_mfma = (ws_size >= off);

  hipMemsetAsync(d_ws, 0, 2048 + (size_t)B * 4, stream);   // colsq + cnt

  if (use_mfma) {
    hipLaunchKernelGGL(k_cast_colsq, dim3(1024), dim3(256), 0, stream,
                       train, train_bf, colsq, N);
    hipLaunchKernelGGL(k_prep, dim3(B), dim3(256), 0, stream,
                       test, colsq, qs, qs_bf, tau, B);
    hipLaunchKernelGGL(k_mfma, dim3((N + 127) / 128), dim3(256), 0, stream,
                       qs_bf, train_bf, tau, cidx, cnt, N, B);
  } else {
    hipLaunchKernelGGL(k_cast_colsq, dim3(1024), dim3(256), 0, stream,
                       train, (__hip_bfloat16*)nullptr, colsq, N);
    hipLaunchKernelGGL(k_prep, dim3(B), dim3(256), 0, stream,
                       test, colsq, qs, qs_bf, tau, B);
    const int CT = (N + 63) / 64;
    const int rb = (B + 127) / 128;
    int bx = 2048 / (rb > 0 ? rb : 1); if (bx < 1) bx = 1;
    int tpc = (CT + bx - 1) / bx;
    int chunks = (CT + tpc - 1) / tpc;
    hipLaunchKernelGGL(k_gemm, dim3(chunks, rb), dim3(256), 0, stream,
                       train, qs, tau, cidx, cnt, N, B, tpc);
  }

  hipLaunchKernelGGL(k_tail, dim3(B), dim3(256), 0, stream,
                     train, qs, cidx, cnt, labels, out, N);
}